// Round 12
// baseline (4900.691 us; speedup 1.0000x reference)
//
#include <hip/hip_runtime.h>

#define BB 4
#define SS 2048
#define DD 1024
#define EE 8
#define HH 2048
#define NTOK (BB*SS)   // 8192 tokens
#define TOT  (NTOK*2)  // 16384 token-slots (top-2)
#define WLMAX (EE + TOT/256)   // 72 max work-list entries

typedef unsigned short u16;
typedef short s16x8 __attribute__((ext_vector_type(8)));
typedef float f32x4 __attribute__((ext_vector_type(4)));
typedef unsigned short us8 __attribute__((ext_vector_type(8)));

typedef __attribute__((address_space(1))) const void gvoid;
typedef __attribute__((address_space(3))) void lvoid;

__device__ inline u16 f2bf(float f) {
    union { float f; unsigned u; } v; v.f = f;
    unsigned r = v.u + 0x7FFFu + ((v.u >> 16) & 1u);   // RNE
    return (u16)(r >> 16);
}
__device__ inline float bf2f(u16 h) {
    union { unsigned u; float f; } v; v.u = ((unsigned)h) << 16;
    return v.f;
}

__device__ inline void gload_lds16(const void* g, void* l) {
    __builtin_amdgcn_global_load_lds((gvoid*)(uintptr_t)g,
                                     (lvoid*)(unsigned)(uintptr_t)l, 16, 0, 0);
}

#define BARRIER() do { asm volatile("" ::: "memory"); \
    __builtin_amdgcn_s_barrier(); \
    asm volatile("" ::: "memory"); } while (0)

// ------------- router (fp32 logits, softmax, top-2) + fused x->bf16 ---------
// No atomics here; counting moved to count_kernel (LDS histogram).
__global__ __launch_bounds__(256) void router_kernel(
    const float* __restrict__ x, const float* __restrict__ Wr,
    const float* __restrict__ br, int* __restrict__ tk_e,
    float* __restrict__ tk_w, u16* __restrict__ Xb)
{
    int wave = threadIdx.x >> 6, lane = threadIdx.x & 63;
    int t = blockIdx.x * 4 + wave;
    const float* xr = x + (size_t)t * DD;
    u16* xb = Xb + (size_t)t * DD;
    float acc[8];
    #pragma unroll
    for (int e = 0; e < 8; e++) acc[e] = 0.f;
    #pragma unroll
    for (int c = 0; c < 4; c++) {
        int dbase = c * 256 + lane * 4;
        float4 v = *(const float4*)(xr + dbase);
        ushort4 o;
        o.x = f2bf(v.x); o.y = f2bf(v.y); o.z = f2bf(v.z); o.w = f2bf(v.w);
        *(ushort4*)(xb + dbase) = o;                       // fused convert
        #pragma unroll
        for (int q = 0; q < 4; q++) {
            float xv = (q == 0) ? v.x : (q == 1) ? v.y : (q == 2) ? v.z : v.w;
            const float4* wr = (const float4*)(Wr + (size_t)(dbase + q) * 8);
            float4 w0 = wr[0], w1 = wr[1];
            acc[0] += xv * w0.x; acc[1] += xv * w0.y;
            acc[2] += xv * w0.z; acc[3] += xv * w0.w;
            acc[4] += xv * w1.x; acc[5] += xv * w1.y;
            acc[6] += xv * w1.z; acc[7] += xv * w1.w;
        }
    }
    #pragma unroll
    for (int off = 32; off > 0; off >>= 1)
        #pragma unroll
        for (int e = 0; e < 8; e++) acc[e] += __shfl_xor(acc[e], off, 64);

    if (lane == 0) {
        float l[8], p[8];
        #pragma unroll
        for (int e = 0; e < 8; e++) l[e] = acc[e] + br[e];
        float mx = l[0];
        #pragma unroll
        for (int e = 1; e < 8; e++) mx = fmaxf(mx, l[e]);
        float s = 0.f;
        #pragma unroll
        for (int e = 0; e < 8; e++) { p[e] = expf(l[e] - mx); s += p[e]; }
        float inv_s = 1.f / s;
        #pragma unroll
        for (int e = 0; e < 8; e++) p[e] *= inv_s;
        int i1 = 0; float p1 = p[0];
        #pragma unroll
        for (int e = 1; e < 8; e++) if (p[e] > p1) { p1 = p[e]; i1 = e; }
        int i2 = -1; float p2 = -1.f;
        #pragma unroll
        for (int e = 0; e < 8; e++) if (e != i1 && p[e] > p2) { p2 = p[e]; i2 = e; }
        float inv = 1.f / (p1 + p2);
        tk_e[2 * t] = i1; tk_e[2 * t + 1] = i2;
        tk_w[2 * t] = p1 * inv; tk_w[2 * t + 1] = p2 * inv;
    }
}

// per-block LDS histogram -> 8 global atomics per block (256 total)
__global__ __launch_bounds__(256) void count_kernel(
    const int* __restrict__ tk_e, int* __restrict__ counts)
{
    __shared__ int hist[EE];
    if (threadIdx.x < EE) hist[threadIdx.x] = 0;
    __syncthreads();
    int t = blockIdx.x * 256 + threadIdx.x;
    atomicAdd(&hist[tk_e[2 * t]], 1);
    atomicAdd(&hist[tk_e[2 * t + 1]], 1);
    __syncthreads();
    if (threadIdx.x < EE) atomicAdd(&counts[threadIdx.x], hist[threadIdx.x]);
}

__global__ void scan_kernel(const int* __restrict__ counts,
                            int* __restrict__ offs, int* __restrict__ cursors,
                            int* __restrict__ wl_e, int* __restrict__ wl_m,
                            int* __restrict__ n_work)
{
    if (threadIdx.x == 0) {
        int o = 0;
        for (int e = 0; e < EE; e++) { offs[e] = o; o += counts[e]; }
        offs[EE] = o;
        int w = 0;
        for (int e = 0; e < EE; e++) {
            int nm = (counts[e] + 255) >> 8;
            for (int m = 0; m < nm; m++) { wl_e[w] = e; wl_m[w] = m; w++; }
        }
        n_work[0] = w;
    }
    if (threadIdx.x < EE) cursors[threadIdx.x] = 0;
}

// wave-aggregated cursor claims: 8 ballots per slot, 1 atomic per (wave,expert)
__global__ __launch_bounds__(256) void scatter_kernel(
    const int* __restrict__ tk_e, const int* __restrict__ offs,
    int* __restrict__ cursors, int* __restrict__ ent_tok,
    int* __restrict__ tok2slot)
{
    int t = blockIdx.x * 256 + threadIdx.x;
    int lane = threadIdx.x & 63;
    #pragma unroll
    for (int s = 0; s < 2; s++) {
        int e = tk_e[2 * t + s];
        unsigned long long m = 0;
        #pragma unroll
        for (int q = 0; q < 8; q++) {
            unsigned long long mq = __ballot(e == q);
            if (e == q) m = mq;
        }
        int leader = __ffsll((long long)m) - 1;
        int cnt = __popcll(m);
        int b = 0;
        if (lane == leader) b = atomicAdd(&cursors[e], cnt);
        b = __shfl(b, leader, 64);
        int rank = __popcll(m & ((1ull << lane) - 1ull));
        int idx = offs[e] + b + rank;
        ent_tok[idx] = t;
        tok2slot[2 * t + s] = idx;
    }
}

// out[t] = w0*Y[slot0] + w1*Y[slot1]
__global__ __launch_bounds__(256) void combine_kernel(
    const u16* __restrict__ Y, const int* __restrict__ tok2slot,
    const float* __restrict__ tk_w, float* __restrict__ out)
{
    int t = blockIdx.x;
    int s0 = tok2slot[2 * t], s1 = tok2slot[2 * t + 1];
    float w0 = tk_w[2 * t], w1 = tk_w[2 * t + 1];
    const ushort4* r0 = (const ushort4*)(Y + (size_t)s0 * DD);
    const ushort4* r1 = (const ushort4*)(Y + (size_t)s1 * DD);
    ushort4 a = r0[threadIdx.x], b = r1[threadIdx.x];
    float4 o;
    o.x = w0 * bf2f(a.x) + w1 * bf2f(b.x);
    o.y = w0 * bf2f(a.y) + w1 * bf2f(b.y);
    o.z = w0 * bf2f(a.z) + w1 * bf2f(b.z);
    o.w = w0 * bf2f(a.w) + w1 * bf2f(b.w);
    ((float4*)(out + (size_t)t * DD))[threadIdx.x] = o;
}

// all 3 weight transposes in ONE launch. R8-proven body (tile[col][row]).
// ranges: [0,4096) W1 (R=DD,C=HH); [4096,12288) W2 (HH,HH); [12288,16384) W3 (HH,DD)
__global__ __launch_bounds__(256) void transpose_all(
    const float* __restrict__ W1, const float* __restrict__ W2,
    const float* __restrict__ W3, u16* __restrict__ W1t,
    u16* __restrict__ W2t, u16* __restrict__ W3t)
{
    __shared__ u16 tile[64][68];
    int id = blockIdx.x;
    const float* in; u16* out; int R, C, rem;
    if (id < 4096)        { in = W1; out = W1t; R = DD; C = HH; rem = id; }
    else if (id < 12288)  { in = W2; out = W2t; R = HH; C = HH; rem = id - 4096; }
    else                  { in = W3; out = W3t; R = HH; C = DD; rem = id - 12288; }
    int nx = C / 64, ny = R / 64;
    int e = rem / (nx * ny); rem %= nx * ny;
    int c0 = (rem % nx) * 64, r0 = (rem / nx) * 64;
    const float* src = in + (size_t)e * R * C;
    u16* dst = out + (size_t)e * R * C;
    int tx = threadIdx.x & 15, ty = threadIdx.x >> 4;
    #pragma unroll
    for (int i = 0; i < 4; i++) {
        int r = i * 16 + ty;
        float4 v = *(const float4*)(src + (size_t)(r0 + r) * C + c0 + tx * 4);
        tile[tx * 4 + 0][r] = f2bf(v.x);
        tile[tx * 4 + 1][r] = f2bf(v.y);
        tile[tx * 4 + 2][r] = f2bf(v.z);
        tile[tx * 4 + 3][r] = f2bf(v.w);
    }
    __syncthreads();
    int tx2 = threadIdx.x & 7, ty2 = threadIdx.x >> 3;   // 8 x 32
    #pragma unroll
    for (int i = 0; i < 2; i++) {
        int c = i * 32 + ty2;
        us8 o = *(const us8*)&tile[c][tx2 * 8];
        *(us8*)(dst + (size_t)(c0 + c) * R + r0 + tx2 * 8) = o;
    }
}

// ---------------- grouped GEMM: 256x256 tile, ring-2, 64KB LDS, 2 blocks/CU -
// 8 waves (2M x 4N), BK=32, distance-2 prefetch, counted vmcnt(4) (0 on last),
// XOR-swizzled LDS (same math as R10). Per tile:
//   vmcnt(N) -> BAR_A -> 12 ds_read -> lgkm(4)+MFMA(m0-3) -> lgkm(0)+MFMA(m4-7)
//   -> BAR_B -> stage(t+2)
// Hazards: slot-t readable after per-wave vmcnt + BAR_A (every wave waited its
// own loads). Overwrite of slot (t&1) by stage(t+2) is after BAR_B, which all
// waves reach only past their lgkm(0) (all reads of slot done).
// EPI 0: OB = bf16(acc+b);  EPI 1: OB = bf16(silu(acc+b)).
template<int KD, int ND, int EPI, bool IND>
__global__ __launch_bounds__(512, 4) void gemm_kernel(
    const u16* __restrict__ A, const u16* __restrict__ Wt,
    const float* __restrict__ bias, u16* __restrict__ OB,
    const int* __restrict__ offs, const int* __restrict__ wl_e,
    const int* __restrict__ wl_m, const int* __restrict__ n_work,
    const int* __restrict__ ent_tok)
{
    constexpr int T = KD / 32;
    static_assert(T >= 8 && (T % 2) == 0, "T assumptions");

    int wid = blockIdx.y;
    if (wid >= n_work[0]) return;
    int e = wl_e[wid];
    int m0 = offs[e] + (wl_m[wid] << 8);
    int mhi = offs[e + 1];
    int n0 = blockIdx.x * 256;

    // ring-2: [slot][A=0/B=1][256 rows * 32 k] bf16 = 64 KB
    __shared__ __align__(16) u16 lds[2][2][256 * 32];

    int tid = threadIdx.x;
    int lane = tid & 63;
    int wave = tid >> 6;
    int wr = wave >> 2, wc = wave & 3;

    // staging source (write-side swizzle via pre-swizzled global k-octet)
    int g_nat = ((tid & 3) ^ ((tid >> 3) & 3)) * 8;
    int arow0 = m0 + (tid >> 2);       if (arow0 >= mhi) arow0 = mhi - 1;
    int arow1 = m0 + 128 + (tid >> 2); if (arow1 >= mhi) arow1 = mhi - 1;
    const u16 *gA0, *gA1;
    if (IND) {
        gA0 = A + (size_t)ent_tok[arow0] * KD + g_nat;
        gA1 = A + (size_t)ent_tok[arow1] * KD + g_nat;
    } else {
        gA0 = A + (size_t)arow0 * KD + g_nat;
        gA1 = A + (size_t)arow1 * KD + g_nat;
    }
    const u16* wbase = Wt + (size_t)e * ND * KD;
    const u16* gB0 = wbase + (size_t)(n0 + (tid >> 2)) * KD + g_nat;
    const u16* gB1 = wbase + (size_t)(n0 + 128 + (tid >> 2)) * KD + g_nat;

    // fragment read offsets (read-side swizzle), u16 elems
    int rsw = (((lane >> 4) ^ (((lane & 15) >> 1) & 3))) * 8;
    int aoff = (wr * 128 + (lane & 15)) * 32 + rsw;
    int boff = (wc * 64 + (lane & 15)) * 32 + rsw;

    f32x4 acc[8][4];
    #pragma unroll
    for (int i = 0; i < 8; i++)
        #pragma unroll
        for (int j = 0; j < 4; j++) acc[i][j] = f32x4{0.f, 0.f, 0.f, 0.f};

#define STAGE(u_, SL) do {                                                    \
    u16* dA_ = &lds[SL][0][0] + wave * 512;                                   \
    u16* dB_ = &lds[SL][1][0] + wave * 512;                                   \
    gload_lds16(gA0 + (size_t)(u_) * 32, dA_);                                \
    gload_lds16(gA1 + (size_t)(u_) * 32, dA_ + 4096);                         \
    gload_lds16(gB0 + (size_t)(u_) * 32, dB_);                                \
    gload_lds16(gB1 + (size_t)(u_) * 32, dB_ + 4096);                         \
} while (0)

    // prologue: stage tiles 0,1
    STAGE(0, 0);
    STAGE(1, 1);

    s16x8 af1[4], af2[4], bq[4];

#define BODY(t_, SL, NW, STG) do {                                            \
    asm volatile("s_waitcnt vmcnt(" NW ")" ::: "memory"); /* tile t landed */ \
    BARRIER();  /* BAR_A: slot SL visible to all waves */                     \
    const u16* sa_ = &lds[SL][0][0];                                          \
    const u16* sb_ = &lds[SL][1][0];                                          \
    _Pragma("unroll")                                                         \
    for (int m_ = 0; m_ < 4; m_++)                                            \
        af1[m_] = *(const s16x8*)(sa_ + aoff + m_ * 512);                     \
    _Pragma("unroll")                                                         \
    for (int n_ = 0; n_ < 4; n_++)                                            \
        bq[n_] = *(const s16x8*)(sb_ + boff + n_ * 512);                      \
    _Pragma("unroll")                                                         \
    for (int m_ = 0; m_ < 4; m_++)                                            \
        af2[m_] = *(const s16x8*)(sa_ + aoff + (m_ + 4) * 512);               \
    asm volatile("s_waitcnt lgkmcnt(4)" ::: "memory");  /* af1,bq done */     \
    __builtin_amdgcn_sched_barrier(0);                                        \
    __builtin_amdgcn_s_setprio(1);                                            \
    _Pragma("unroll")                                                         \
    for (int m_ = 0; m_ < 4; m_++)                                            \
        _Pragma("unroll")                                                     \
        for (int n_ = 0; n_ < 4; n_++)                                        \
            acc[m_][n_] = __builtin_amdgcn_mfma_f32_16x16x32_bf16(            \
                af1[m_], bq[n_], acc[m_][n_], 0, 0, 0);                       \
    __builtin_amdgcn_s_setprio(0);                                            \
    asm volatile("s_waitcnt lgkmcnt(0)" ::: "memory");  /* all reads done */  \
    __builtin_amdgcn_sched_barrier(0);                                        \
    __builtin_amdgcn_s_setprio(1);                                            \
    _Pragma("unroll")                                                         \
    for (int m_ = 0; m_ < 4; m_++)                                            \
        _Pragma("unroll")                                                     \
        for (int n_ = 0; n_ < 4; n_++)                                        \
            acc[m_ + 4][n_] = __builtin_amdgcn_mfma_f32_16x16x32_bf16(        \
                af2[m_], bq[n_], acc[m_ + 4][n_], 0, 0, 0);                   \
    __builtin_amdgcn_s_setprio(0);                                            \
    BARRIER();  /* BAR_B: all waves done reading slot SL */                   \
    if (STG) STAGE((t_) + 2, SL);   /* overwrite slot SL: safe past BAR_B */  \
} while (0)

    // main: bodies 0..T-3 stage t+2 (vmcnt(4): leave tile t+1's 4 in flight)
    for (int tt = 0; tt + 2 < T; tt += 2) {
        BODY(tt,     0, "4", 1);
        BODY(tt + 1, 1, "4", 1);
    }
    BODY(T - 2, 0, "4", 0);   // outstanding: T-2(4), T-1(4) -> leave 4
    BODY(T - 1, 1, "0", 0);   // outstanding: T-1(4) -> drain
#undef BODY
#undef STAGE

    // epilogue
    const float* bvec = bias + (size_t)e * ND;
    float bv[4];
    #pragma unroll
    for (int n = 0; n < 4; n++)
        bv[n] = bvec[n0 + wc * 64 + n * 16 + (lane & 15)];

    #pragma unroll
    for (int m = 0; m < 8; m++) {
        #pragma unroll
        for (int r = 0; r < 4; r++) {
            int row = m0 + wr * 128 + m * 16 + (lane >> 4) * 4 + r;
            if (row >= mhi) continue;
            #pragma unroll
            for (int n = 0; n < 4; n++) {
                int col = n0 + wc * 64 + n * 16 + (lane & 15);
                float v = acc[m][n][r] + bv[n];
                if (EPI == 1) v = v / (1.f + __expf(-v));   // silu (fast exp)
                OB[(size_t)row * ND + col] = f2bf(v);
            }
        }
    }
}

extern "C" void kernel_launch(void* const* d_in, const int* in_sizes, int n_in,
                              void* d_out, int out_size, void* d_ws, size_t ws_size,
                              hipStream_t stream) {
    const float* x  = (const float*)d_in[0];
    const float* Wr = (const float*)d_in[1];
    const float* br = (const float*)d_in[2];
    const float* W1 = (const float*)d_in[3];
    const float* b1 = (const float*)d_in[4];
    const float* W2 = (const float*)d_in[5];
    const float* b2 = (const float*)d_in[6];
    const float* W3 = (const float*)d_in[7];
    const float* b3 = (const float*)d_in[8];
    float* out = (float*)d_out;

    char* ws = (char*)d_ws;
    size_t off = 0;
    auto alloc = [&](size_t bytes) {
        char* p = ws + off;
        off = (off + bytes + 255) & ~(size_t)255;
        return p;
    };
    // ctrl: counts[0:8] cursors[8:16] offs[16:25] n_work[25] wl_e[32:104] wl_m[104:176]
    int*   ctrl     = (int*)alloc(1024);
    int*   counts   = ctrl;
    int*   cursors  = ctrl + 8;
    int*   offs     = ctrl + 16;
    int*   n_work   = ctrl + 25;
    int*   wl_e     = ctrl + 32;
    int*   wl_m     = ctrl + 104;
    int*   tk_e     = (int*)  alloc((size_t)NTOK * 2 * sizeof(int));
    float* tk_w     = (float*)alloc((size_t)NTOK * 2 * sizeof(float));
    int*   ent_tok  = (int*)  alloc((size_t)TOT * sizeof(int));
    int*   tok2slot = (int*)  alloc((size_t)NTOK * 2 * sizeof(int));
    u16*   Xb       = (u16*)  alloc((size_t)NTOK * DD * 2);
    u16*   Yg       = (u16*)  alloc((size_t)TOT * DD * 2);
    u16*   H1       = (u16*)  alloc((size_t)TOT * HH * 2);
    u16*   A2       = (u16*)  alloc((size_t)TOT * HH * 2);
    u16*   W1t      = (u16*)  alloc((size_t)EE * HH * DD * 2);
    u16*   W2t      = (u16*)  alloc((size_t)EE * HH * HH * 2);
    u16*   W3t      = (u16*)  alloc((size_t)EE * DD * HH * 2);

    hipMemsetAsync(ctrl, 0, 1024, stream);

    transpose_all<<<16384, 256, 0, stream>>>(W1, W2, W3, W1t, W2t, W3t);

    router_kernel<<<NTOK / 4, 256, 0, stream>>>(x, Wr, br, tk_e, tk_w, Xb);
    count_kernel<<<NTOK / 256, 256, 0, stream>>>(tk_e, counts);
    scan_kernel<<<1, 64, 0, stream>>>(counts, offs, cursors, wl_e, wl_m, n_work);
    scatter_kernel<<<NTOK / 256, 256, 0, stream>>>(tk_e, offs, cursors, ent_tok, tok2slot);

    gemm_kernel<DD, HH, 0, true><<<dim3(HH / 256, WLMAX, 1), 512, 0, stream>>>(
        Xb, W1t, b1, H1, offs, wl_e, wl_m, n_work, ent_tok);
    gemm_kernel<HH, HH, 1, false><<<dim3(HH / 256, WLMAX, 1), 512, 0, stream>>>(
        H1, W2t, b2, A2, offs, wl_e, wl_m, n_work, nullptr);
    gemm_kernel<HH, DD, 0, false><<<dim3(DD / 256, WLMAX, 1), 512, 0, stream>>>(
        A2, W3t, b3, Yg, offs, wl_e, wl_m, n_work, nullptr);

    combine_kernel<<<NTOK, 256, 0, stream>>>(Yg, tok2slot, tk_w, out);
}

// Round 13
// 523.427 us; speedup vs baseline: 9.3627x; 9.3627x over previous
//
#include <hip/hip_runtime.h>

#define BB 4
#define SS 2048
#define DD 1024
#define EE 8
#define HH 2048
#define NTOK (BB*SS)   // 8192 tokens
#define TOT  (NTOK*2)  // 16384 token-slots (top-2)
#define WLMAX (EE + TOT/256)   // 72 max work-list entries

typedef unsigned short u16;
typedef short s16x8 __attribute__((ext_vector_type(8)));
typedef float f32x4 __attribute__((ext_vector_type(4)));
typedef unsigned short us8 __attribute__((ext_vector_type(8)));

typedef __attribute__((address_space(1))) const void gvoid;
typedef __attribute__((address_space(3))) void lvoid;

__device__ inline u16 f2bf(float f) {
    union { float f; unsigned u; } v; v.f = f;
    unsigned r = v.u + 0x7FFFu + ((v.u >> 16) & 1u);   // RNE
    return (u16)(r >> 16);
}
__device__ inline float bf2f(u16 h) {
    union { unsigned u; float f; } v; v.u = ((unsigned)h) << 16;
    return v.f;
}

__device__ inline void gload_lds16(const void* g, void* l) {
    __builtin_amdgcn_global_load_lds((gvoid*)(uintptr_t)g,
                                     (lvoid*)(unsigned)(uintptr_t)l, 16, 0, 0);
}

#define BARRIER() do { asm volatile("" ::: "memory"); \
    __builtin_amdgcn_s_barrier(); \
    asm volatile("" ::: "memory"); } while (0)

// ------------- router (fp32 logits, softmax, top-2) + fused x->bf16 ---------
__global__ __launch_bounds__(256) void router_kernel(
    const float* __restrict__ x, const float* __restrict__ Wr,
    const float* __restrict__ br, int* __restrict__ tk_e,
    float* __restrict__ tk_w, u16* __restrict__ Xb)
{
    int wave = threadIdx.x >> 6, lane = threadIdx.x & 63;
    int t = blockIdx.x * 4 + wave;
    const float* xr = x + (size_t)t * DD;
    u16* xb = Xb + (size_t)t * DD;
    float acc[8];
    #pragma unroll
    for (int e = 0; e < 8; e++) acc[e] = 0.f;
    #pragma unroll
    for (int c = 0; c < 4; c++) {
        int dbase = c * 256 + lane * 4;
        float4 v = *(const float4*)(xr + dbase);
        ushort4 o;
        o.x = f2bf(v.x); o.y = f2bf(v.y); o.z = f2bf(v.z); o.w = f2bf(v.w);
        *(ushort4*)(xb + dbase) = o;                       // fused convert
        #pragma unroll
        for (int q = 0; q < 4; q++) {
            float xv = (q == 0) ? v.x : (q == 1) ? v.y : (q == 2) ? v.z : v.w;
            const float4* wr = (const float4*)(Wr + (size_t)(dbase + q) * 8);
            float4 w0 = wr[0], w1 = wr[1];
            acc[0] += xv * w0.x; acc[1] += xv * w0.y;
            acc[2] += xv * w0.z; acc[3] += xv * w0.w;
            acc[4] += xv * w1.x; acc[5] += xv * w1.y;
            acc[6] += xv * w1.z; acc[7] += xv * w1.w;
        }
    }
    #pragma unroll
    for (int off = 32; off > 0; off >>= 1)
        #pragma unroll
        for (int e = 0; e < 8; e++) acc[e] += __shfl_xor(acc[e], off, 64);

    if (lane == 0) {
        float l[8], p[8];
        #pragma unroll
        for (int e = 0; e < 8; e++) l[e] = acc[e] + br[e];
        float mx = l[0];
        #pragma unroll
        for (int e = 1; e < 8; e++) mx = fmaxf(mx, l[e]);
        float s = 0.f;
        #pragma unroll
        for (int e = 0; e < 8; e++) { p[e] = expf(l[e] - mx); s += p[e]; }
        float inv_s = 1.f / s;
        #pragma unroll
        for (int e = 0; e < 8; e++) p[e] *= inv_s;
        int i1 = 0; float p1 = p[0];
        #pragma unroll
        for (int e = 1; e < 8; e++) if (p[e] > p1) { p1 = p[e]; i1 = e; }
        int i2 = -1; float p2 = -1.f;
        #pragma unroll
        for (int e = 0; e < 8; e++) if (e != i1 && p[e] > p2) { p2 = p[e]; i2 = e; }
        float inv = 1.f / (p1 + p2);
        tk_e[2 * t] = i1; tk_e[2 * t + 1] = i2;
        tk_w[2 * t] = p1 * inv; tk_w[2 * t + 1] = p2 * inv;
    }
}

// per-block LDS histogram -> 8 global atomics per block
__global__ __launch_bounds__(256) void count_kernel(
    const int* __restrict__ tk_e, int* __restrict__ counts)
{
    __shared__ int hist[EE];
    if (threadIdx.x < EE) hist[threadIdx.x] = 0;
    __syncthreads();
    int t = blockIdx.x * 256 + threadIdx.x;
    atomicAdd(&hist[tk_e[2 * t]], 1);
    atomicAdd(&hist[tk_e[2 * t + 1]], 1);
    __syncthreads();
    if (threadIdx.x < EE) atomicAdd(&counts[threadIdx.x], hist[threadIdx.x]);
}

__global__ void scan_kernel(const int* __restrict__ counts,
                            int* __restrict__ offs, int* __restrict__ cursors,
                            int* __restrict__ wl_e, int* __restrict__ wl_m,
                            int* __restrict__ n_work)
{
    if (threadIdx.x == 0) {
        int o = 0;
        for (int e = 0; e < EE; e++) { offs[e] = o; o += counts[e]; }
        offs[EE] = o;
        int w = 0;
        for (int e = 0; e < EE; e++) {
            int nm = (counts[e] + 255) >> 8;
            for (int m = 0; m < nm; m++) { wl_e[w] = e; wl_m[w] = m; w++; }
        }
        n_work[0] = w;
    }
    if (threadIdx.x < EE) cursors[threadIdx.x] = 0;
}

// wave-aggregated cursor claims: 1 atomic per (wave,expert) instead of per token
__global__ __launch_bounds__(256) void scatter_kernel(
    const int* __restrict__ tk_e, const int* __restrict__ offs,
    int* __restrict__ cursors, int* __restrict__ ent_tok,
    int* __restrict__ tok2slot)
{
    int t = blockIdx.x * 256 + threadIdx.x;
    int lane = threadIdx.x & 63;
    #pragma unroll
    for (int s = 0; s < 2; s++) {
        int e = tk_e[2 * t + s];
        unsigned long long m = 0;
        #pragma unroll
        for (int q = 0; q < 8; q++) {
            unsigned long long mq = __ballot(e == q);
            if (e == q) m = mq;
        }
        int leader = __ffsll((long long)m) - 1;
        int cnt = __popcll(m);
        int b = 0;
        if (lane == leader) b = atomicAdd(&cursors[e], cnt);
        b = __shfl(b, leader, 64);
        int rank = __popcll(m & ((1ull << lane) - 1ull));
        int idx = offs[e] + b + rank;
        ent_tok[idx] = t;
        tok2slot[2 * t + s] = idx;
    }
}

// out[t] = w0*Y[slot0] + w1*Y[slot1]
__global__ __launch_bounds__(256) void combine_kernel(
    const u16* __restrict__ Y, const int* __restrict__ tok2slot,
    const float* __restrict__ tk_w, float* __restrict__ out)
{
    int t = blockIdx.x;
    int s0 = tok2slot[2 * t], s1 = tok2slot[2 * t + 1];
    float w0 = tk_w[2 * t], w1 = tk_w[2 * t + 1];
    const ushort4* r0 = (const ushort4*)(Y + (size_t)s0 * DD);
    const ushort4* r1 = (const ushort4*)(Y + (size_t)s1 * DD);
    ushort4 a = r0[threadIdx.x], b = r1[threadIdx.x];
    float4 o;
    o.x = w0 * bf2f(a.x) + w1 * bf2f(b.x);
    o.y = w0 * bf2f(a.y) + w1 * bf2f(b.y);
    o.z = w0 * bf2f(a.z) + w1 * bf2f(b.z);
    o.w = w0 * bf2f(a.w) + w1 * bf2f(b.w);
    ((float4*)(out + (size_t)t * DD))[threadIdx.x] = o;
}

// all 3 weight transposes in ONE launch. R8-proven body (tile[col][row]).
__global__ __launch_bounds__(256) void transpose_all(
    const float* __restrict__ W1, const float* __restrict__ W2,
    const float* __restrict__ W3, u16* __restrict__ W1t,
    u16* __restrict__ W2t, u16* __restrict__ W3t)
{
    __shared__ u16 tile[64][68];
    int id = blockIdx.x;
    const float* in; u16* out; int R, C, rem;
    if (id < 4096)        { in = W1; out = W1t; R = DD; C = HH; rem = id; }
    else if (id < 12288)  { in = W2; out = W2t; R = HH; C = HH; rem = id - 4096; }
    else                  { in = W3; out = W3t; R = HH; C = DD; rem = id - 12288; }
    int nx = C / 64, ny = R / 64;
    int e = rem / (nx * ny); rem %= nx * ny;
    int c0 = (rem % nx) * 64, r0 = (rem / nx) * 64;
    const float* src = in + (size_t)e * R * C;
    u16* dst = out + (size_t)e * R * C;
    int tx = threadIdx.x & 15, ty = threadIdx.x >> 4;
    #pragma unroll
    for (int i = 0; i < 4; i++) {
        int r = i * 16 + ty;
        float4 v = *(const float4*)(src + (size_t)(r0 + r) * C + c0 + tx * 4);
        tile[tx * 4 + 0][r] = f2bf(v.x);
        tile[tx * 4 + 1][r] = f2bf(v.y);
        tile[tx * 4 + 2][r] = f2bf(v.z);
        tile[tx * 4 + 3][r] = f2bf(v.w);
    }
    __syncthreads();
    int tx2 = threadIdx.x & 7, ty2 = threadIdx.x >> 3;   // 8 x 32
    #pragma unroll
    for (int i = 0; i < 2; i++) {
        int c = i * 32 + ty2;
        us8 o = *(const us8*)&tile[c][tx2 * 8];
        *(us8*)(dst + (size_t)(c0 + c) * R + r0 + tx2 * 8) = o;
    }
}

// ---------------- grouped GEMM: R10-proven body, verbatim -------------------
// 256x256 tile, 8 waves (2M x 4N), BK=32, ring-4 LDS slots, distance-3
// prefetch, counted vmcnt (8/4/0 peel) + lgkm, XOR-swizzled LDS,
// __launch_bounds__(512,2) (128 arch VGPR + AGPR acc fits; R12's (512,4)
// forced a 64-reg split and spilled the accumulator -> 5GB scratch).
// EPI 0: OB = bf16(acc + b);  EPI 1: OB = bf16(silu(acc + b)).
template<int KD, int ND, int EPI, bool IND>
__global__ __launch_bounds__(512, 2) void gemm_kernel(
    const u16* __restrict__ A, const u16* __restrict__ Wt,
    const float* __restrict__ bias, u16* __restrict__ OB,
    const int* __restrict__ offs, const int* __restrict__ wl_e,
    const int* __restrict__ wl_m, const int* __restrict__ n_work,
    const int* __restrict__ ent_tok)
{
    constexpr int T = KD / 32;
    static_assert(T >= 8 && (T % 4) == 0, "T assumptions");

    int wid = blockIdx.y;
    if (wid >= n_work[0]) return;
    int e = wl_e[wid];
    int m0 = offs[e] + (wl_m[wid] << 8);
    int mhi = offs[e + 1];
    int n0 = blockIdx.x * 256;

    __shared__ __align__(16) u16 lds[4][2][256 * 32];

    int tid = threadIdx.x;
    int lane = tid & 63;
    int wave = tid >> 6;
    int wr = wave >> 2, wc = wave & 3;

    int g_nat = ((tid & 3) ^ ((tid >> 3) & 3)) * 8;
    int arow0 = m0 + (tid >> 2);       if (arow0 >= mhi) arow0 = mhi - 1;
    int arow1 = m0 + 128 + (tid >> 2); if (arow1 >= mhi) arow1 = mhi - 1;
    const u16 *gA0, *gA1;
    if (IND) {
        gA0 = A + (size_t)ent_tok[arow0] * KD + g_nat;
        gA1 = A + (size_t)ent_tok[arow1] * KD + g_nat;
    } else {
        gA0 = A + (size_t)arow0 * KD + g_nat;
        gA1 = A + (size_t)arow1 * KD + g_nat;
    }
    const u16* wbase = Wt + (size_t)e * ND * KD;
    const u16* gB0 = wbase + (size_t)(n0 + (tid >> 2)) * KD + g_nat;
    const u16* gB1 = wbase + (size_t)(n0 + 128 + (tid >> 2)) * KD + g_nat;

    int rsw = (((lane >> 4) ^ (((lane & 15) >> 1) & 3))) * 8;
    int aoff = (wr * 128 + (lane & 15)) * 32 + rsw;
    int boff = (wc * 64 + (lane & 15)) * 32 + rsw;

    f32x4 acc[8][4];
    #pragma unroll
    for (int i = 0; i < 8; i++)
        #pragma unroll
        for (int j = 0; j < 4; j++) acc[i][j] = f32x4{0.f, 0.f, 0.f, 0.f};

    #pragma unroll
    for (int u = 0; u < 3; u++) {
        u16* dA = &lds[u][0][0] + wave * 512;
        u16* dB = &lds[u][1][0] + wave * 512;
        gload_lds16(gA0 + (size_t)u * 32, dA);
        gload_lds16(gA1 + (size_t)u * 32, dA + 4096);
        gload_lds16(gB0 + (size_t)u * 32, dB);
        gload_lds16(gB1 + (size_t)u * 32, dB + 4096);
    }

    s16x8 af1[4], af2[4], bqA[4], bqB[4];
    asm volatile("s_waitcnt vmcnt(8)" ::: "memory");
    BARRIER();
    {
        const u16* sa = &lds[0][0][0];
        const u16* sb = &lds[0][1][0];
        #pragma unroll
        for (int m_ = 0; m_ < 4; m_++) af1[m_] = *(const s16x8*)(sa + aoff + m_ * 512);
        #pragma unroll
        for (int n_ = 0; n_ < 4; n_++) bqA[n_] = *(const s16x8*)(sb + boff + n_ * 512);
    }

#define TILE_BODY(t_, BQC, BQN, NWSTR, STG, LAST) do {                        \
    BARRIER();  /* BAR_A: slot (t-1)%4 reads complete in all waves */         \
    const u16* sa_ = &lds[(t_) & 3][0][0];                                    \
    _Pragma("unroll")                                                         \
    for (int m_ = 0; m_ < 4; m_++)                                            \
        af2[m_] = *(const s16x8*)(sa_ + aoff + (m_ + 4) * 512);               \
    if (STG) {                                                                \
        u16* dA_ = &lds[((t_) + 3) & 3][0][0] + wave * 512;                   \
        u16* dB_ = &lds[((t_) + 3) & 3][1][0] + wave * 512;                   \
        gload_lds16(gA0 + (size_t)((t_) + 3) * 32, dA_);                      \
        gload_lds16(gA1 + (size_t)((t_) + 3) * 32, dA_ + 4096);               \
        gload_lds16(gB0 + (size_t)((t_) + 3) * 32, dB_);                      \
        gload_lds16(gB1 + (size_t)((t_) + 3) * 32, dB_ + 4096);               \
    }                                                                         \
    asm volatile("s_waitcnt lgkmcnt(4)" ::: "memory");  /* af1,BQC done */    \
    __builtin_amdgcn_sched_barrier(0);                                        \
    __builtin_amdgcn_s_setprio(1);                                            \
    _Pragma("unroll")                                                         \
    for (int m_ = 0; m_ < 4; m_++)                                            \
        _Pragma("unroll")                                                     \
        for (int n_ = 0; n_ < 4; n_++)                                        \
            acc[m_][n_] = __builtin_amdgcn_mfma_f32_16x16x32_bf16(            \
                af1[m_], BQC[n_], acc[m_][n_], 0, 0, 0);                      \
    __builtin_amdgcn_s_setprio(0);                                            \
    asm volatile("s_waitcnt vmcnt(" NWSTR ")" ::: "memory"); /* t+1 landed */ \
    BARRIER();  /* BAR_B: tile t+1 now safe for ALL waves */                  \
    if (!(LAST)) {                                                            \
        const u16* na_ = &lds[((t_) + 1) & 3][0][0];                          \
        const u16* nb_ = &lds[((t_) + 1) & 3][1][0];                          \
        _Pragma("unroll")                                                     \
        for (int m_ = 0; m_ < 4; m_++)                                        \
            af1[m_] = *(const s16x8*)(na_ + aoff + m_ * 512);                 \
        _Pragma("unroll")                                                     \
        for (int n_ = 0; n_ < 4; n_++)                                        \
            BQN[n_] = *(const s16x8*)(nb_ + boff + n_ * 512);                 \
        asm volatile("s_waitcnt lgkmcnt(8)" ::: "memory");  /* af2 done */    \
    } else {                                                                  \
        asm volatile("s_waitcnt lgkmcnt(0)" ::: "memory");                    \
    }                                                                         \
    __builtin_amdgcn_sched_barrier(0);                                        \
    __builtin_amdgcn_s_setprio(1);                                            \
    _Pragma("unroll")                                                         \
    for (int m_ = 0; m_ < 4; m_++)                                            \
        _Pragma("unroll")                                                     \
        for (int n_ = 0; n_ < 4; n_++)                                        \
            acc[m_ + 4][n_] = __builtin_amdgcn_mfma_f32_16x16x32_bf16(        \
                af2[m_], BQC[n_], acc[m_ + 4][n_], 0, 0, 0);                  \
    __builtin_amdgcn_s_setprio(0);                                            \
} while (0)

    int t = 0;
    for (; t <= T - 6; t += 2) {
        TILE_BODY(t,     bqA, bqB, "8", 1, 0);
        TILE_BODY(t + 1, bqB, bqA, "8", 1, 0);
    }
    TILE_BODY(T - 4, bqA, bqB, "8", 1, 0);
    TILE_BODY(T - 3, bqB, bqA, "4", 0, 0);
    TILE_BODY(T - 2, bqA, bqB, "0", 0, 0);
    TILE_BODY(T - 1, bqB, bqA, "0", 0, 1);
#undef TILE_BODY

    const float* bvec = bias + (size_t)e * ND;
    float bv[4];
    #pragma unroll
    for (int n = 0; n < 4; n++)
        bv[n] = bvec[n0 + wc * 64 + n * 16 + (lane & 15)];

    #pragma unroll
    for (int m = 0; m < 8; m++) {
        #pragma unroll
        for (int r = 0; r < 4; r++) {
            int row = m0 + wr * 128 + m * 16 + (lane >> 4) * 4 + r;
            if (row >= mhi) continue;
            #pragma unroll
            for (int n = 0; n < 4; n++) {
                int col = n0 + wc * 64 + n * 16 + (lane & 15);
                float v = acc[m][n][r] + bv[n];
                if (EPI == 1) v = v / (1.f + __expf(-v));   // silu
                OB[(size_t)row * ND + col] = f2bf(v);
            }
        }
    }
}

extern "C" void kernel_launch(void* const* d_in, const int* in_sizes, int n_in,
                              void* d_out, int out_size, void* d_ws, size_t ws_size,
                              hipStream_t stream) {
    const float* x  = (const float*)d_in[0];
    const float* Wr = (const float*)d_in[1];
    const float* br = (const float*)d_in[2];
    const float* W1 = (const float*)d_in[3];
    const float* b1 = (const float*)d_in[4];
    const float* W2 = (const float*)d_in[5];
    const float* b2 = (const float*)d_in[6];
    const float* W3 = (const float*)d_in[7];
    const float* b3 = (const float*)d_in[8];
    float* out = (float*)d_out;

    char* ws = (char*)d_ws;
    size_t off = 0;
    auto alloc = [&](size_t bytes) {
        char* p = ws + off;
        off = (off + bytes + 255) & ~(size_t)255;
        return p;
    };
    // ctrl: counts[0:8] cursors[8:16] offs[16:25] n_work[25] wl_e[32:104] wl_m[104:176]
    int*   ctrl     = (int*)alloc(1024);
    int*   counts   = ctrl;
    int*   cursors  = ctrl + 8;
    int*   offs     = ctrl + 16;
    int*   n_work   = ctrl + 25;
    int*   wl_e     = ctrl + 32;
    int*   wl_m     = ctrl + 104;
    int*   tk_e     = (int*)  alloc((size_t)NTOK * 2 * sizeof(int));
    float* tk_w     = (float*)alloc((size_t)NTOK * 2 * sizeof(float));
    int*   ent_tok  = (int*)  alloc((size_t)TOT * sizeof(int));
    int*   tok2slot = (int*)  alloc((size_t)NTOK * 2 * sizeof(int));
    u16*   Xb       = (u16*)  alloc((size_t)NTOK * DD * 2);
    u16*   Yg       = (u16*)  alloc((size_t)TOT * DD * 2);
    u16*   H1       = (u16*)  alloc((size_t)TOT * HH * 2);
    u16*   A2       = (u16*)  alloc((size_t)TOT * HH * 2);
    u16*   W1t      = (u16*)  alloc((size_t)EE * HH * DD * 2);
    u16*   W2t      = (u16*)  alloc((size_t)EE * HH * HH * 2);
    u16*   W3t      = (u16*)  alloc((size_t)EE * DD * HH * 2);

    hipMemsetAsync(ctrl, 0, 1024, stream);

    transpose_all<<<16384, 256, 0, stream>>>(W1, W2, W3, W1t, W2t, W3t);

    router_kernel<<<NTOK / 4, 256, 0, stream>>>(x, Wr, br, tk_e, tk_w, Xb);
    count_kernel<<<NTOK / 256, 256, 0, stream>>>(tk_e, counts);
    scan_kernel<<<1, 64, 0, stream>>>(counts, offs, cursors, wl_e, wl_m, n_work);
    scatter_kernel<<<NTOK / 256, 256, 0, stream>>>(tk_e, offs, cursors, ent_tok, tok2slot);

    gemm_kernel<DD, HH, 0, true><<<dim3(HH / 256, WLMAX, 1), 512, 0, stream>>>(
        Xb, W1t, b1, H1, offs, wl_e, wl_m, n_work, ent_tok);
    gemm_kernel<HH, HH, 1, false><<<dim3(HH / 256, WLMAX, 1), 512, 0, stream>>>(
        H1, W2t, b2, A2, offs, wl_e, wl_m, n_work, nullptr);
    gemm_kernel<HH, DD, 0, false><<<dim3(DD / 256, WLMAX, 1), 512, 0, stream>>>(
        A2, W3t, b3, Yg, offs, wl_e, wl_m, n_work, nullptr);

    combine_kernel<<<NTOK, 256, 0, stream>>>(Yg, tok2slot, tk_w, out);
}